// Round 1
// baseline (210.331 us; speedup 1.0000x reference)
//
#include <hip/hip_runtime.h>
#include <math.h>

#define V 16384
#define D 256
#define NH 256
#define THREE_NH 768
#define IDIM 1024
#define LN_EPS 1e-12f

typedef short s16x8 __attribute__((ext_vector_type(8)));
typedef float f32x4 __attribute__((ext_vector_type(4)));

__device__ inline unsigned short f2bf(float f) {
    unsigned u = __float_as_uint(f);
    u += 0x7fffu + ((u >> 16) & 1u);          // RNE
    return (unsigned short)(u >> 16);
}
__device__ inline float bf2f(unsigned short s) {
    return __uint_as_float(((unsigned)s) << 16);
}
__device__ inline float bflo(unsigned v) { return __uint_as_float(v << 16); }
__device__ inline float bfhi(unsigned v) { return __uint_as_float(v & 0xffff0000u); }

// async global->LDS, 16B per lane. LDS dest = wave-uniform base + lane*16.
__device__ inline void gl2lds16(const unsigned short* g, unsigned short* l) {
    __builtin_amdgcn_global_load_lds(
        (__attribute__((address_space(1))) void*)(g),
        (__attribute__((address_space(3))) void*)(l), 16, 0, 0);
}

// Stage ROWS_T x 64 bf16 tile (row-major, leading dim ldk) into LDS.
// 16B chunk c of row r stored at chunk slot c ^ (r&7) (XOR swizzle on the
// global side; LDS write order stays lane-contiguous for global_load_lds).
template <int ROWS_T>
__device__ inline void stage(const unsigned short* __restrict__ src, size_t row0,
                             int ldk, int k0, unsigned short* lds, int wv, int lane) {
    constexpr int PER_WAVE = ROWS_T / 32;     // 1KB segments per wave
    #pragma unroll
    for (int i = 0; i < PER_WAVE; ++i) {
        const int seg = wv * PER_WAVE + i;
        const int r = seg * 8 + (lane >> 3);
        const int c = (lane & 7) ^ (r & 7);
        gl2lds16(src + (row0 + (size_t)r) * ldk + k0 + c * 8, lds + seg * 512);
    }
}

// read one 8-elem bf16 fragment (16B) for (row, chunk) from swizzled tile
__device__ inline s16x8 fragld(const unsigned short* lds, int row, int chunk) {
    return *(const s16x8*)&lds[row * 64 + ((chunk ^ (row & 7)) << 3)];
}

// direct global B-fragment load: rows (nbase+l16) of Bt (N x K), 16B at k.
// Per wave-instruction: 16 rows x 64 contiguous bytes -> fully coalesced L2 hits.
__device__ inline s16x8 bfrag(const unsigned short* __restrict__ Bt, int K,
                              int nbase, int l16, int k0, int chunk) {
    return *(const s16x8*)&Bt[(size_t)(nbase + l16) * K + k0 + (chunk << 3)];
}

// ---------------------------------------------------------------------------
// prep: one launch for all conversions.
// blocks [0,768): W transposes (fp32 KxN -> bf16 NxK); [768,4864): X -> bf16.
// ---------------------------------------------------------------------------
__global__ __launch_bounds__(256) void prep(const float* __restrict__ X,
                                            unsigned short* __restrict__ Xb,
                                            const float* __restrict__ Wqkv,
                                            const float* __restrict__ Wo,
                                            const float* __restrict__ Wi,
                                            const float* __restrict__ Wo2,
                                            unsigned short* __restrict__ WqkvT,
                                            unsigned short* __restrict__ WoT,
                                            unsigned short* __restrict__ WiT,
                                            unsigned short* __restrict__ Wo2T) {
    const int b = blockIdx.x, t = threadIdx.x;
    if (b >= 768) {
        int i = (b - 768) * 256 + t;
        float4 v = ((const float4*)X)[i];
        ushort4 o;
        o.x = f2bf(v.x); o.y = f2bf(v.y); o.z = f2bf(v.z); o.w = f2bf(v.w);
        ((ushort4*)Xb)[i] = o;
        return;
    }
    __shared__ float tile[32][33];
    const float* W; unsigned short* Wt; int K, N, bx, by;
    if (b < 192)      { W = Wqkv; Wt = WqkvT; K = 256;  N = 768;  bx = b & 7;          by = b >> 3; }
    else if (b < 256) { W = Wo;   Wt = WoT;   K = 256;  N = 256;  bx = (b - 192) & 7;  by = (b - 192) >> 3; }
    else if (b < 512) { W = Wi;   Wt = WiT;   K = 256;  N = 1024; bx = (b - 256) & 7;  by = (b - 256) >> 3; }
    else              { W = Wo2;  Wt = Wo2T;  K = 1024; N = 256;  bx = (b - 512) & 31; by = (b - 512) >> 5; }
    const int k0 = bx * 32, n0 = by * 32;
    #pragma unroll
    for (int p = 0; p < 4; ++p) {
        int idx = t + p * 256, r = idx >> 5, c = idx & 31;
        tile[r][c] = W[(size_t)(k0 + r) * N + n0 + c];
    }
    __syncthreads();
    #pragma unroll
    for (int p = 0; p < 4; ++p) {
        int idx = t + p * 256, r = idx >> 5, c = idx & 31;
        Wt[(size_t)(n0 + r) * K + k0 + c] = f2bf(tile[c][r]);
    }
}

// ---------------------------------------------------------------------------
// gemmW<K,N,EPI>: C(bf16, MxN) = A(bf16, MxK) @ Bt(bf16, NxK)^T
// B is an L2-resident weight: loaded DIRECT global->VGPR (coalesced fragment
// pattern), no LDS, no per-step barriers. A staged to LDS ONCE per block
// (K=256 -> 64 KB). One barrier per block. 128x256 tile, 4 waves 2x2 of
// 64x128 (acc[4][8]).  EPI: 0 = none, 1 = exact gelu.
// ---------------------------------------------------------------------------
template <int K, int N, int EPI>
__global__ __launch_bounds__(256, 2) void gemmW(const unsigned short* __restrict__ A,
                                                const unsigned short* __restrict__ Bt,
                                                unsigned short* __restrict__ C) {
    __shared__ unsigned short As[128 * K];    // K=256 -> 64 KB, 4 swizzled 64-col tiles
    const int t = threadIdx.x;
    const int r0 = blockIdx.x * 128, c0 = blockIdx.y * 256;
    const int wv = t >> 6, lane = t & 63, q = lane >> 4, l16 = lane & 15;
    const int wr = (wv >> 1) * 64, wc = (wv & 1) * 128;
    f32x4 acc[4][8] = {};

    #pragma unroll
    for (int kc = 0; kc < K / 64; ++kc)
        stage<128>(A, (size_t)r0, K, kc * 64, As + kc * 8192, wv, lane);
    __builtin_amdgcn_s_waitcnt(0);
    __syncthreads();

    #pragma unroll
    for (int kc = 0; kc < K / 64; ++kc) {
        const unsigned short* Ak = As + kc * 8192;
        #pragma unroll
        for (int kk2 = 0; kk2 < 2; ++kk2) {
            s16x8 af[4];
            #pragma unroll
            for (int mf = 0; mf < 4; ++mf)
                af[mf] = fragld(Ak, wr + mf * 16 + l16, kk2 * 4 + q);
            #pragma unroll
            for (int nf = 0; nf < 8; ++nf) {
                const s16x8 bv = bfrag(Bt, K, c0 + wc + nf * 16, l16, kc * 64, kk2 * 4 + q);
                #pragma unroll
                for (int mf = 0; mf < 4; ++mf)
                    acc[mf][nf] = __builtin_amdgcn_mfma_f32_16x16x32_bf16(af[mf], bv, acc[mf][nf], 0, 0, 0);
            }
        }
    }

    #pragma unroll
    for (int mf = 0; mf < 4; ++mf)
        #pragma unroll
        for (int nf = 0; nf < 8; ++nf) {
            const int cg = c0 + wc + nf * 16 + l16;
            #pragma unroll
            for (int r = 0; r < 4; ++r) {
                const int rg = r0 + wr + mf * 16 + q * 4 + r;
                float v = acc[mf][nf][r];
                if (EPI == 1) v = 0.5f * v * (1.f + erff(v * 0.70710678118654752f));
                C[(size_t)rg * N + cg] = f2bf(v);
            }
        }
}

// ---------------------------------------------------------------------------
// gemm_wo2ln: out(fp32) = LN(A(bf16,Mx1024) @ Wo2T(256x1024)^T + resb(bf16)).
// BM=64, BN=256 (full row in one block -> fused LN). B direct from global.
// A chunked 4x256, double-buffered LDS with counted vmcnt(8) prefetch.
// 4 waves, each 64 rows x 64 cols (acc[4][4]); cross-wave LN reduce.
// ---------------------------------------------------------------------------
__global__ __launch_bounds__(256, 2) void gemm_wo2ln(const unsigned short* __restrict__ A,
                                                     const unsigned short* __restrict__ Bt,
                                                     const unsigned short* __restrict__ resb,
                                                     const float* __restrict__ gamma,
                                                     const float* __restrict__ beta,
                                                     float* __restrict__ out) {
    __shared__ unsigned short As[2][64 * 256];    // 2 x 32 KB
    __shared__ float2 partial[4][64];
    __shared__ float2 stats[64];
    const int t = threadIdx.x, r0 = blockIdx.x * 64;
    const int wv = t >> 6, lane = t & 63, q = lane >> 4, l16 = lane & 15;
    const int wc = wv * 64;
    f32x4 acc[4][4] = {};

    // prologue: stage chunk 0 (8 loads/wave)
    #pragma unroll
    for (int kc = 0; kc < 4; ++kc)
        stage<64>(A, (size_t)r0, IDIM, kc * 64, As[0] + kc * 4096, wv, lane);

    #pragma unroll
    for (int ch = 0; ch < 4; ++ch) {
        const unsigned short* Ac = As[ch & 1];
        if (ch < 3) {
            #pragma unroll
            for (int kc = 0; kc < 4; ++kc)
                stage<64>(A, (size_t)r0, IDIM, (ch + 1) * 256 + kc * 64,
                          As[(ch & 1) ^ 1] + kc * 4096, wv, lane);
            asm volatile("s_waitcnt vmcnt(8)" ::: "memory");   // cur chunk landed
        } else {
            asm volatile("s_waitcnt vmcnt(0)" ::: "memory");
        }
        __syncthreads();
        #pragma unroll
        for (int kc = 0; kc < 4; ++kc) {
            const unsigned short* Ak = Ac + kc * 4096;
            const int kg = ch * 256 + kc * 64;
            #pragma unroll
            for (int kk2 = 0; kk2 < 2; ++kk2) {
                s16x8 af[4];
                #pragma unroll
                for (int mf = 0; mf < 4; ++mf)
                    af[mf] = fragld(Ak, mf * 16 + l16, kk2 * 4 + q);
                #pragma unroll
                for (int nf = 0; nf < 4; ++nf) {
                    const s16x8 bv = bfrag(Bt, IDIM, wc + nf * 16, l16, kg, kk2 * 4 + q);
                    #pragma unroll
                    for (int mf = 0; mf < 4; ++mf)
                        acc[mf][nf] = __builtin_amdgcn_mfma_f32_16x16x32_bf16(af[mf], bv, acc[mf][nf], 0, 0, 0);
                }
            }
        }
        __syncthreads();   // all waves done with cur buffer before it is restaged
    }

    // + residual (bf16) before LN stats
    #pragma unroll
    for (int mf = 0; mf < 4; ++mf)
        #pragma unroll
        for (int nf = 0; nf < 4; ++nf) {
            const int cg = wc + nf * 16 + l16;
            #pragma unroll
            for (int r = 0; r < 4; ++r)
                acc[mf][nf][r] += bf2f(resb[(size_t)(r0 + mf * 16 + q * 4 + r) * NH + cg]);
        }

    // per-row partial sums over this wave's 64 cols (reduce across 16-lane quad)
    #pragma unroll
    for (int mf = 0; mf < 4; ++mf) {
        float s[4] = {0.f, 0.f, 0.f, 0.f}, ss[4] = {0.f, 0.f, 0.f, 0.f};
        #pragma unroll
        for (int nf = 0; nf < 4; ++nf)
            #pragma unroll
            for (int r = 0; r < 4; ++r) {
                float v = acc[mf][nf][r];
                s[r] += v; ss[r] += v * v;
            }
        #pragma unroll
        for (int off = 1; off < 16; off <<= 1)
            #pragma unroll
            for (int r = 0; r < 4; ++r) {
                s[r]  += __shfl_xor(s[r],  off);
                ss[r] += __shfl_xor(ss[r], off);
            }
        if (l16 == 0)
            #pragma unroll
            for (int r = 0; r < 4; ++r)
                partial[wv][mf * 16 + q * 4 + r] = make_float2(s[r], ss[r]);
    }
    __syncthreads();
    if (t < 64) {
        float sv = 0.f, ssv = 0.f;
        #pragma unroll
        for (int w = 0; w < 4; ++w) { sv += partial[w][t].x; ssv += partial[w][t].y; }
        float mu  = sv * (1.f / 256.f);
        float var = ssv * (1.f / 256.f) - mu * mu;
        stats[t] = make_float2(mu, rsqrtf(var + LN_EPS));
    }
    __syncthreads();

    #pragma unroll
    for (int mf = 0; mf < 4; ++mf)
        #pragma unroll
        for (int nf = 0; nf < 4; ++nf) {
            const int cg = wc + nf * 16 + l16;
            const float g = gamma[cg], b = beta[cg];
            #pragma unroll
            for (int r = 0; r < 4; ++r) {
                const int rl = mf * 16 + q * 4 + r;
                const float2 st = stats[rl];
                out[(size_t)(r0 + rl) * NH + cg] = (acc[mf][nf][r] - st.x) * st.y * g + b;
            }
        }
}

// ---------------------------------------------------------------------------
// FUSED attention + W_o GEMM + LN1. One block per group (32 nodes).
// Phase A (attention): qkv group tile in LDS (stride 776), register-blocked
//   scores, register softmax via shfl_xor(8/16), P via padded bf16 LDS,
//   PV -> o[4][8] in registers.
// Bridge: o written bf16 into an LDS A-tile in stage()/fragld() layout
//   (4 tiles of 32x64, XOR chunk swizzle), overlaying the dead qkv region.
// Phase B: WoT read DIRECT from global (L2-resident, 128 KB) -> no B staging,
//   no in-loop barriers. Residual X (fp32), fused LN, write bf16 preb.
// ---------------------------------------------------------------------------
#define LDR 776
__global__ __launch_bounds__(256) void attln(const unsigned short* __restrict__ qkv,
                                             const unsigned short* __restrict__ WoT,
                                             const float* __restrict__ X,
                                             const float* __restrict__ gamma,
                                             const float* __restrict__ beta,
                                             unsigned short* __restrict__ preb) {
    __shared__ unsigned short smem[33536 + 320];    // 24832 (s) + 8704 (pt) + stats
    unsigned short* s  = smem;                      // attn qkv tile, stride LDR
    unsigned short* pt = smem + 24832;              // P tiles, 8*32*34
    unsigned short* at = smem;                      // phase B: A tile (4 x 32x64)
    float2* partial = (float2*)(smem + 24832);      // overlays pt (dead in phase B)
    float2* stats   = (float2*)(smem + 24832 + 512);

    const int g = blockIdx.x;
    const int t = threadIdx.x;
    const int h = t >> 5, u = t & 31;
    const int ub = u & 7;          // row set: ub + 8*di
    const int us = u >> 3;         // score cols: us + 4*dj ; PV d0 = us*8
    const int qc = h * 96;         // q col base; k at +32; v at +64

    // ---- load: group's qkv is 24576 contiguous ushorts; 16B per lane ----
    const unsigned short* src = qkv + (size_t)g * 32 * THREE_NH;
    #pragma unroll
    for (int pp = 0; pp < 12; ++pp) {
        int c = t + pp * 256;                  // chunk id 0..3071
        int row = c / 96, col8 = c % 96;
        s16x8 vv = *(const s16x8*)&src[c * 8];
        *(s16x8*)&s[row * LDR + col8 * 8] = vv;
    }
    __syncthreads();

    // ---- scores ----
    float sc[4][8];
    #pragma unroll
    for (int di = 0; di < 4; ++di)
        #pragma unroll
        for (int dj = 0; dj < 8; ++dj) sc[di][dj] = 0.f;

    for (int kq = 0; kq < 8; ++kq) {
        float qv[4][4];
        #pragma unroll
        for (int di = 0; di < 4; ++di) {
            uint2 v = *(const uint2*)&s[(ub + 8 * di) * LDR + qc + 4 * kq];
            qv[di][0] = bflo(v.x); qv[di][1] = bfhi(v.x);
            qv[di][2] = bflo(v.y); qv[di][3] = bfhi(v.y);
        }
        #pragma unroll
        for (int dj = 0; dj < 8; ++dj) {
            uint2 v = *(const uint2*)&s[(us + 4 * dj) * LDR + qc + 32 + 4 * kq];
            float kv[4];
            kv[0] = bflo(v.x); kv[1] = bfhi(v.x);
            kv[2] = bflo(v.y); kv[3] = bfhi(v.y);
            #pragma unroll
            for (int di = 0; di < 4; ++di)
                #pragma unroll
                for (int kk = 0; kk < 4; ++kk)
                    sc[di][dj] = fmaf(qv[di][kk], kv[kk], sc[di][dj]);
        }
    }

    // ---- softmax per row ----
    #pragma unroll
    for (int di = 0; di < 4; ++di) {
        float m = sc[di][0];
        #pragma unroll
        for (int dj = 1; dj < 8; ++dj) m = fmaxf(m, sc[di][dj]);
        m = fmaxf(m, __shfl_xor(m, 8));
        m = fmaxf(m, __shfl_xor(m, 16));
        float sum = 0.f;
        #pragma unroll
        for (int dj = 0; dj < 8; ++dj) {
            float e = __expf((sc[di][dj] - m) * 0.17677669529663687f);
            sc[di][dj] = e;
            sum += e;
        }
        sum += __shfl_xor(sum, 8);
        sum += __shfl_xor(sum, 16);
        float inv = 1.f / sum;
        const int rb = h * 1088 + (ub + 8 * di) * 34;
        #pragma unroll
        for (int dj = 0; dj < 8; ++dj)
            pt[rb + us + 4 * dj] = f2bf(sc[di][dj] * inv);
    }
    __syncthreads();

    // ---- PV ----
    const int vc = qc + 64, d0 = us * 8;
    float o[4][8];
    #pragma unroll
    for (int di = 0; di < 4; ++di)
        #pragma unroll
        for (int dd = 0; dd < 8; ++dd) o[di][dd] = 0.f;

    for (int j = 0; j < 32; ++j) {
        float pv[4];
        #pragma unroll
        for (int di = 0; di < 4; ++di)
            pv[di] = bf2f(pt[h * 1088 + (ub + 8 * di) * 34 + j]);
        #pragma unroll
        for (int dq = 0; dq < 2; ++dq) {
            uint2 v = *(const uint2*)&s[j * LDR + vc + d0 + 4 * dq];
            float v0 = bflo(v.x), v1 = bfhi(v.x), v2 = bflo(v.y), v3 = bfhi(v.y);
            #pragma unroll
            for (int di = 0; di < 4; ++di) {
                o[di][dq * 4 + 0] = fmaf(pv[di], v0, o[di][dq * 4 + 0]);
                o[di][dq * 4 + 1] = fmaf(pv[di], v1, o[di][dq * 4 + 1]);
                o[di][dq * 4 + 2] = fmaf(pv[di], v2, o[di][dq * 4 + 2]);
                o[di][dq * 4 + 3] = fmaf(pv[di], v3, o[di][dq * 4 + 3]);
            }
        }
    }
    __syncthreads();   // all reads of s/pt done before overwriting with at

    // ---- bridge: o -> at (swizzled A layout) ----
    {
        const int col = h * 32 + d0;           // 8-col chunk this thread owns
        const int kb = col >> 6, c = (col & 63) >> 3;
        #pragma unroll
        for (int di = 0; di < 4; ++di) {
            const int i = ub + 8 * di;
            s16x8 ov;
            #pragma unroll
            for (int dd = 0; dd < 8; ++dd) ov[dd] = (short)f2bf(o[di][dd]);
            *(s16x8*)&at[kb * 2048 + i * 64 + ((c ^ (i & 7)) << 3)] = ov;
        }
    }
    __syncthreads();   // at visible to all waves before phase B reads

    // ---- phase B: pre = LN(at @ WoT^T + X), write bf16. B direct global. ----
    const int wv = t >> 6, lane = t & 63, q = lane >> 4, l16 = lane & 15;
    const int wc = wv * 64;
    const int r0 = g * 32;
    f32x4 acc[2][4] = {};

    #pragma unroll
    for (int kc = 0; kc < 4; ++kc) {
        const unsigned short* atk = at + kc * 2048;
        #pragma unroll
        for (int kk2 = 0; kk2 < 2; ++kk2) {
            s16x8 af[2];
            #pragma unroll
            for (int mf = 0; mf < 2; ++mf)
                af[mf] = fragld(atk, mf * 16 + l16, kk2 * 4 + q);
            #pragma unroll
            for (int nf = 0; nf < 4; ++nf) {
                const s16x8 bv = bfrag(WoT, NH, wc + nf * 16, l16, kc * 64, kk2 * 4 + q);
                #pragma unroll
                for (int mf = 0; mf < 2; ++mf)
                    acc[mf][nf] = __builtin_amdgcn_mfma_f32_16x16x32_bf16(af[mf], bv, acc[mf][nf], 0, 0, 0);
            }
        }
    }

    // + residual X (fp32)
    #pragma unroll
    for (int mf = 0; mf < 2; ++mf)
        #pragma unroll
        for (int nf = 0; nf < 4; ++nf) {
            const int cg = wc + nf * 16 + l16;
            #pragma unroll
            for (int r = 0; r < 4; ++r)
                acc[mf][nf][r] += X[(size_t)(r0 + mf * 16 + q * 4 + r) * NH + cg];
        }

    // LN partial sums
    #pragma unroll
    for (int mf = 0; mf < 2; ++mf) {
        float sp[4] = {0.f, 0.f, 0.f, 0.f}, ssp[4] = {0.f, 0.f, 0.f, 0.f};
        #pragma unroll
        for (int nf = 0; nf < 4; ++nf)
            #pragma unroll
            for (int r = 0; r < 4; ++r) {
                float v = acc[mf][nf][r];
                sp[r] += v; ssp[r] += v * v;
            }
        #pragma unroll
        for (int off = 1; off < 16; off <<= 1)
            #pragma unroll
            for (int r = 0; r < 4; ++r) {
                sp[r]  += __shfl_xor(sp[r],  off);
                ssp[r] += __shfl_xor(ssp[r], off);
            }
        if (l16 == 0)
            #pragma unroll
            for (int r = 0; r < 4; ++r)
                partial[wv * 32 + mf * 16 + q * 4 + r] = make_float2(sp[r], ssp[r]);
    }
    __syncthreads();
    if (t < 32) {
        float sv = 0.f, ssv = 0.f;
        #pragma unroll
        for (int w = 0; w < 4; ++w) { sv += partial[w * 32 + t].x; ssv += partial[w * 32 + t].y; }
        float mu  = sv * (1.f / 256.f);
        float var = ssv * (1.f / 256.f) - mu * mu;
        stats[t] = make_float2(mu, rsqrtf(var + LN_EPS));
    }
    __syncthreads();

    #pragma unroll
    for (int mf = 0; mf < 2; ++mf)
        #pragma unroll
        for (int nf = 0; nf < 4; ++nf) {
            const int cg = wc + nf * 16 + l16;
            const float gm = gamma[cg], bt = beta[cg];
            #pragma unroll
            for (int r = 0; r < 4; ++r) {
                const int rl = mf * 16 + q * 4 + r;
                const float2 st = stats[rl];
                float v = (acc[mf][nf][r] - st.x) * st.y * gm + bt;
                preb[(size_t)(r0 + rl) * NH + cg] = f2bf(v);
            }
        }
}

// ---------------------------------------------------------------------------
extern "C" void kernel_launch(void* const* d_in, const int* in_sizes, int n_in,
                              void* d_out, int out_size, void* d_ws, size_t ws_size,
                              hipStream_t stream) {
    const float* X      = (const float*)d_in[0];
    const float* W_qkv  = (const float*)d_in[2];
    const float* W_o    = (const float*)d_in[3];
    const float* ln1_g  = (const float*)d_in[4];
    const float* ln1_b  = (const float*)d_in[5];
    const float* W_i    = (const float*)d_in[6];
    const float* W_out2 = (const float*)d_in[7];
    const float* ln2_g  = (const float*)d_in[8];
    const float* ln2_b  = (const float*)d_in[9];
    float* out = (float*)d_out;

    char* ws = (char*)d_ws;
    unsigned short* Xbf   = (unsigned short*)(ws);                 //  8.0 MB
    unsigned short* qkvb  = (unsigned short*)(ws + 8388608);       // 25.2 MB
    unsigned short* preb  = (unsigned short*)(ws + 58720256);      //  8.0 MB
    unsigned short* WqkvT = (unsigned short*)(ws + 67108864);
    unsigned short* WoT   = (unsigned short*)(ws + 67502080);
    unsigned short* WiT   = (unsigned short*)(ws + 67633152);
    unsigned short* Wo2T  = (unsigned short*)(ws + 68157440);
    unsigned short* interb = (unsigned short*)(ws);                // 33.5 MB alias (Xbf+qkvb dead)

    dim3 blk(256);
    hipLaunchKernelGGL(prep, dim3(768 + V * D / 4 / 256), blk, 0, stream,
                       X, Xbf, W_qkv, W_o, W_i, W_out2, WqkvT, WoT, WiT, Wo2T);

    hipLaunchKernelGGL((gemmW<D, THREE_NH, 0>), dim3(V / 128, THREE_NH / 256), blk, 0, stream,
                       Xbf, WqkvT, qkvb);
    hipLaunchKernelGGL(attln, dim3(V / 32), blk, 0, stream,
                       qkvb, WoT, X, ln1_g, ln1_b, preb);
    hipLaunchKernelGGL((gemmW<D, IDIM, 1>), dim3(V / 128, IDIM / 256), blk, 0, stream,
                       preb, WiT, interb);
    hipLaunchKernelGGL(gemm_wo2ln, dim3(V / 64), blk, 0, stream,
                       interb, Wo2T, preb, ln2_g, ln2_b, out);
}

// Round 2
// 158.475 us; speedup vs baseline: 1.3272x; 1.3272x over previous
//
#include <hip/hip_runtime.h>
#include <math.h>

#define V 16384
#define D 256
#define NH 256
#define THREE_NH 768
#define IDIM 1024
#define LN_EPS 1e-12f

typedef short s16x8 __attribute__((ext_vector_type(8)));
typedef float f32x4 __attribute__((ext_vector_type(4)));

__device__ inline unsigned short f2bf(float f) {
    unsigned u = __float_as_uint(f);
    u += 0x7fffu + ((u >> 16) & 1u);          // RNE
    return (unsigned short)(u >> 16);
}
__device__ inline float bf2f(unsigned short s) {
    return __uint_as_float(((unsigned)s) << 16);
}
__device__ inline float bflo(unsigned v) { return __uint_as_float(v << 16); }
__device__ inline float bfhi(unsigned v) { return __uint_as_float(v & 0xffff0000u); }

// async global->LDS, 16B per lane. LDS dest = wave-uniform base + lane*16.
__device__ inline void gl2lds16(const unsigned short* g, unsigned short* l) {
    __builtin_amdgcn_global_load_lds(
        (__attribute__((address_space(1))) void*)(g),
        (__attribute__((address_space(3))) void*)(l), 16, 0, 0);
}

// Stage ROWS_T x 64 bf16 tile (row-major, leading dim ldk) into LDS.
// 16B chunk c of row r stored at chunk slot c ^ (r&7) (XOR swizzle on the
// global side; LDS write order stays lane-contiguous for global_load_lds).
template <int ROWS_T>
__device__ inline void stage(const unsigned short* __restrict__ src, size_t row0,
                             int ldk, int k0, unsigned short* lds, int wv, int lane) {
    constexpr int PER_WAVE = ROWS_T / 32;     // 1KB segments per wave
    #pragma unroll
    for (int i = 0; i < PER_WAVE; ++i) {
        const int seg = wv * PER_WAVE + i;
        const int r = seg * 8 + (lane >> 3);
        const int c = (lane & 7) ^ (r & 7);
        gl2lds16(src + (row0 + (size_t)r) * ldk + k0 + c * 8, lds + seg * 512);
    }
}

// read one 8-elem bf16 fragment (16B) for (row, chunk) from swizzled tile
__device__ inline s16x8 fragld(const unsigned short* lds, int row, int chunk) {
    return *(const s16x8*)&lds[row * 64 + ((chunk ^ (row & 7)) << 3)];
}

// ---------------------------------------------------------------------------
// prep: one launch for all conversions.
// blocks [0,768): W transposes (fp32 KxN -> bf16 NxK); [768,4864): X -> bf16.
// ---------------------------------------------------------------------------
__global__ __launch_bounds__(256) void prep(const float* __restrict__ X,
                                            unsigned short* __restrict__ Xb,
                                            const float* __restrict__ Wqkv,
                                            const float* __restrict__ Wo,
                                            const float* __restrict__ Wi,
                                            const float* __restrict__ Wo2,
                                            unsigned short* __restrict__ WqkvT,
                                            unsigned short* __restrict__ WoT,
                                            unsigned short* __restrict__ WiT,
                                            unsigned short* __restrict__ Wo2T) {
    const int b = blockIdx.x, t = threadIdx.x;
    if (b >= 768) {
        int i = (b - 768) * 256 + t;
        float4 v = ((const float4*)X)[i];
        ushort4 o;
        o.x = f2bf(v.x); o.y = f2bf(v.y); o.z = f2bf(v.z); o.w = f2bf(v.w);
        ((ushort4*)Xb)[i] = o;
        return;
    }
    __shared__ float tile[32][33];
    const float* W; unsigned short* Wt; int K, N, bx, by;
    if (b < 192)      { W = Wqkv; Wt = WqkvT; K = 256;  N = 768;  bx = b & 7;          by = b >> 3; }
    else if (b < 256) { W = Wo;   Wt = WoT;   K = 256;  N = 256;  bx = (b - 192) & 7;  by = (b - 192) >> 3; }
    else if (b < 512) { W = Wi;   Wt = WiT;   K = 256;  N = 1024; bx = (b - 256) & 7;  by = (b - 256) >> 3; }
    else              { W = Wo2;  Wt = Wo2T;  K = 1024; N = 256;  bx = (b - 512) & 31; by = (b - 512) >> 5; }
    const int k0 = bx * 32, n0 = by * 32;
    #pragma unroll
    for (int p = 0; p < 4; ++p) {
        int idx = t + p * 256, r = idx >> 5, c = idx & 31;
        tile[r][c] = W[(size_t)(k0 + r) * N + n0 + c];
    }
    __syncthreads();
    #pragma unroll
    for (int p = 0; p < 4; ++p) {
        int idx = t + p * 256, r = idx >> 5, c = idx & 31;
        Wt[(size_t)(n0 + r) * K + k0 + c] = f2bf(tile[c][r]);
    }
}

// ---------------------------------------------------------------------------
// gemm128<K,N,EPI>: C(bf16, MxN) = A(bf16, MxK) @ Bt(bf16, NxK)^T
// EPI: 0 = none, 1 = exact gelu.  128x128 tile, BK=64, 4 waves of 64x64.
// 1-D grid + XCD row-band swizzle: XCD x (= blockIdx%8) owns row-tiles
// [x*16, x*16+16), iterating column-tiles fastest -> per-XCD working set
// (1MB A-band + B) stays L2-resident; A fetched from HBM ~once instead of
// N/128 times.  Requires M = 16384 (128 row-tiles = 8 XCDs x 16).
// ---------------------------------------------------------------------------
template <int K, int N, int EPI>
__global__ __launch_bounds__(256) void gemm128(const unsigned short* __restrict__ A,
                                               const unsigned short* __restrict__ Bt,
                                               unsigned short* __restrict__ C) {
    __shared__ unsigned short As[128 * 64];
    __shared__ unsigned short Bs[128 * 64];
    constexpr int NCOL = N / 128;
    const int b = blockIdx.x;
    const int idx = b >> 3;
    const int r0 = ((b & 7) * 16 + idx / NCOL) * 128;
    const int c0 = (idx % NCOL) * 128;
    const int t = threadIdx.x;
    const int wv = t >> 6, lane = t & 63, q = lane >> 4, l16 = lane & 15;
    const int wr = (wv >> 1) * 64, wc = (wv & 1) * 64;
    f32x4 acc[4][4] = {};

    for (int k0 = 0; k0 < K; k0 += 64) {
        __syncthreads();
        stage<128>(A,  (size_t)r0, K, k0, As, wv, lane);
        stage<128>(Bt, (size_t)c0, K, k0, Bs, wv, lane);
        __builtin_amdgcn_s_waitcnt(0);
        __syncthreads();
        #pragma unroll
        for (int kk2 = 0; kk2 < 2; ++kk2) {
            s16x8 af[4], bfr[4];
            #pragma unroll
            for (int mf = 0; mf < 4; ++mf)
                af[mf] = fragld(As, wr + mf * 16 + l16, kk2 * 4 + q);
            #pragma unroll
            for (int nf = 0; nf < 4; ++nf)
                bfr[nf] = fragld(Bs, wc + nf * 16 + l16, kk2 * 4 + q);
            #pragma unroll
            for (int mf = 0; mf < 4; ++mf)
                #pragma unroll
                for (int nf = 0; nf < 4; ++nf)
                    acc[mf][nf] = __builtin_amdgcn_mfma_f32_16x16x32_bf16(af[mf], bfr[nf], acc[mf][nf], 0, 0, 0);
        }
    }

    #pragma unroll
    for (int mf = 0; mf < 4; ++mf)
        #pragma unroll
        for (int nf = 0; nf < 4; ++nf) {
            const int cg = c0 + wc + nf * 16 + l16;
            #pragma unroll
            for (int r = 0; r < 4; ++r) {
                const int rg = r0 + wr + mf * 16 + q * 4 + r;
                float v = acc[mf][nf][r];
                if (EPI == 1) v = 0.5f * v * (1.f + erff(v * 0.70710678118654752f));
                C[(size_t)rg * N + cg] = f2bf(v);
            }
        }
}

// ---------------------------------------------------------------------------
// gemm_ln<K,OUTF,RESBF>: out = LN(A(bf16,MxK) @ Bt(bf16,256xK)^T + res); N=256.
// BM=32, BN=256, 4 waves each 32 rows x 64 cols; fused row LN across waves.
// BK=128 (two 64-col subtiles per iteration): halves the number of exposed
// stage->drain->barrier rounds (16 -> 8 at K=1024).  LDS 73KB -> still 2
// blocks/CU, which the 512-block grid caps at anyway.
// ---------------------------------------------------------------------------
template <int K, bool OUTF, bool RESBF>
__global__ __launch_bounds__(256) void gemm_ln(const unsigned short* __restrict__ A,
                                               const unsigned short* __restrict__ Bt,
                                               const void* __restrict__ resv,
                                               const float* __restrict__ gamma,
                                               const float* __restrict__ beta,
                                               float* __restrict__ outf,
                                               unsigned short* __restrict__ outb) {
    __shared__ unsigned short As[2][32 * 64];
    __shared__ unsigned short Bs[2][256 * 64];
    __shared__ float2 partial[4][32];
    __shared__ float2 stats[32];
    const int t = threadIdx.x, r0 = blockIdx.x * 32;
    const int wv = t >> 6, lane = t & 63, q = lane >> 4, l16 = lane & 15;
    const int wc = wv * 64;
    f32x4 acc[2][4] = {};

    for (int k0 = 0; k0 < K; k0 += 128) {
        __syncthreads();
        stage<32>(A, (size_t)r0, K, k0,      As[0], wv, lane);
        stage<32>(A, (size_t)r0, K, k0 + 64, As[1], wv, lane);
        stage<256>(Bt, 0, K, k0,      Bs[0], wv, lane);
        stage<256>(Bt, 0, K, k0 + 64, Bs[1], wv, lane);
        __builtin_amdgcn_s_waitcnt(0);
        __syncthreads();
        #pragma unroll
        for (int sub = 0; sub < 2; ++sub) {
            #pragma unroll
            for (int kk2 = 0; kk2 < 2; ++kk2) {
                s16x8 af[2], bfr[4];
                #pragma unroll
                for (int mf = 0; mf < 2; ++mf)
                    af[mf] = fragld(As[sub], mf * 16 + l16, kk2 * 4 + q);
                #pragma unroll
                for (int nf = 0; nf < 4; ++nf)
                    bfr[nf] = fragld(Bs[sub], wc + nf * 16 + l16, kk2 * 4 + q);
                #pragma unroll
                for (int mf = 0; mf < 2; ++mf)
                    #pragma unroll
                    for (int nf = 0; nf < 4; ++nf)
                        acc[mf][nf] = __builtin_amdgcn_mfma_f32_16x16x32_bf16(af[mf], bfr[nf], acc[mf][nf], 0, 0, 0);
            }
        }
    }

    // + residual (before LN stats)
    #pragma unroll
    for (int mf = 0; mf < 2; ++mf)
        #pragma unroll
        for (int nf = 0; nf < 4; ++nf) {
            const int cg = wc + nf * 16 + l16;
            #pragma unroll
            for (int r = 0; r < 4; ++r) {
                const size_t idx = (size_t)(r0 + mf * 16 + q * 4 + r) * NH + cg;
                float rv;
                if (RESBF) rv = bf2f(((const unsigned short*)resv)[idx]);
                else       rv = ((const float*)resv)[idx];
                acc[mf][nf][r] += rv;
            }
        }

    // per-row partial sums over this wave's 64 cols (reduce across 16-lane quad)
    #pragma unroll
    for (int mf = 0; mf < 2; ++mf) {
        float s[4] = {0.f, 0.f, 0.f, 0.f}, ss[4] = {0.f, 0.f, 0.f, 0.f};
        #pragma unroll
        for (int nf = 0; nf < 4; ++nf)
            #pragma unroll
            for (int r = 0; r < 4; ++r) {
                float v = acc[mf][nf][r];
                s[r] += v; ss[r] += v * v;
            }
        #pragma unroll
        for (int off = 1; off < 16; off <<= 1)
            #pragma unroll
            for (int r = 0; r < 4; ++r) {
                s[r]  += __shfl_xor(s[r],  off);
                ss[r] += __shfl_xor(ss[r], off);
            }
        if (l16 == 0)
            #pragma unroll
            for (int r = 0; r < 4; ++r)
                partial[wv][mf * 16 + q * 4 + r] = make_float2(s[r], ss[r]);
    }
    __syncthreads();
    if (t < 32) {
        float s = 0.f, ss = 0.f;
        #pragma unroll
        for (int w = 0; w < 4; ++w) { s += partial[w][t].x; ss += partial[w][t].y; }
        float mu  = s * (1.f / 256.f);
        float var = ss * (1.f / 256.f) - mu * mu;
        stats[t] = make_float2(mu, rsqrtf(var + LN_EPS));
    }
    __syncthreads();

    #pragma unroll
    for (int mf = 0; mf < 2; ++mf)
        #pragma unroll
        for (int nf = 0; nf < 4; ++nf) {
            const int cg = wc + nf * 16 + l16;
            const float g = gamma[cg], b = beta[cg];
            #pragma unroll
            for (int r = 0; r < 4; ++r) {
                const int rl = mf * 16 + q * 4 + r;
                const float2 st = stats[rl];
                float v = (acc[mf][nf][r] - st.x) * st.y * g + b;
                const size_t idx = (size_t)(r0 + rl) * NH + cg;
                if (OUTF) outf[idx] = v;
                else      outb[idx] = f2bf(v);
            }
        }
}

// ---------------------------------------------------------------------------
// FUSED attention + W_o GEMM + LN1. One block per group (32 nodes).
// Phase A (attention): qkv group tile in LDS (stride 776), register-blocked
//   scores, register softmax via shfl_xor(8/16), P via padded bf16 LDS,
//   PV -> o[4][8] in registers.
// Bridge: o written bf16 into an LDS A-tile in stage()/fragld() layout
//   (4 tiles of 32x64, XOR chunk swizzle), overlaying the dead qkv region.
// Phase B (= gemm_ln<256> body): A from LDS, B=WoT staged per k0, residual X
//   (fp32), fused LN, write bf16 preb.
// LDS: max(qkv 48.5K + P 17K, at 16K + Bs 32K + stats 1.3K) = 65.5 KB.
// ---------------------------------------------------------------------------
#define LDR 776
__global__ __launch_bounds__(256) void attln(const unsigned short* __restrict__ qkv,
                                             const unsigned short* __restrict__ WoT,
                                             const float* __restrict__ X,
                                             const float* __restrict__ gamma,
                                             const float* __restrict__ beta,
                                             unsigned short* __restrict__ preb) {
    __shared__ unsigned short smem[33536 + 320];    // 24832 (s) + 8704 (pt) + stats
    unsigned short* s  = smem;                      // attn qkv tile, stride LDR
    unsigned short* pt = smem + 24832;              // P tiles, 8*32*34
    unsigned short* at = smem;                      // phase B: A tile (4 x 32x64)
    unsigned short* Bs = smem + 8192;               // phase B: B stage (256x64)
    float2* partial = (float2*)(smem + 24832);      // overlays pt (dead in phase B)
    float2* stats   = (float2*)(smem + 24832 + 512);

    const int g = blockIdx.x;
    const int t = threadIdx.x;
    const int h = t >> 5, u = t & 31;
    const int ub = u & 7;          // row set: ub + 8*di
    const int us = u >> 3;         // score cols: us + 4*dj ; PV d0 = us*8
    const int qc = h * 96;         // q col base; k at +32; v at +64

    // ---- load: group's qkv is 24576 contiguous ushorts; 16B per lane ----
    const unsigned short* src = qkv + (size_t)g * 32 * THREE_NH;
    #pragma unroll
    for (int pp = 0; pp < 12; ++pp) {
        int c = t + pp * 256;                  // chunk id 0..3071
        int row = c / 96, col8 = c % 96;
        s16x8 vv = *(const s16x8*)&src[c * 8];
        *(s16x8*)&s[row * LDR + col8 * 8] = vv;
    }
    __syncthreads();

    // ---- scores ----
    float sc[4][8];
    #pragma unroll
    for (int di = 0; di < 4; ++di)
        #pragma unroll
        for (int dj = 0; dj < 8; ++dj) sc[di][dj] = 0.f;

    for (int kq = 0; kq < 8; ++kq) {
        float qv[4][4];
        #pragma unroll
        for (int di = 0; di < 4; ++di) {
            uint2 v = *(const uint2*)&s[(ub + 8 * di) * LDR + qc + 4 * kq];
            qv[di][0] = bflo(v.x); qv[di][1] = bfhi(v.x);
            qv[di][2] = bflo(v.y); qv[di][3] = bfhi(v.y);
        }
        #pragma unroll
        for (int dj = 0; dj < 8; ++dj) {
            uint2 v = *(const uint2*)&s[(us + 4 * dj) * LDR + qc + 32 + 4 * kq];
            float kv[4];
            kv[0] = bflo(v.x); kv[1] = bfhi(v.x);
            kv[2] = bflo(v.y); kv[3] = bfhi(v.y);
            #pragma unroll
            for (int di = 0; di < 4; ++di)
                #pragma unroll
                for (int kk = 0; kk < 4; ++kk)
                    sc[di][dj] = fmaf(qv[di][kk], kv[kk], sc[di][dj]);
        }
    }

    // ---- softmax per row ----
    #pragma unroll
    for (int di = 0; di < 4; ++di) {
        float m = sc[di][0];
        #pragma unroll
        for (int dj = 1; dj < 8; ++dj) m = fmaxf(m, sc[di][dj]);
        m = fmaxf(m, __shfl_xor(m, 8));
        m = fmaxf(m, __shfl_xor(m, 16));
        float sum = 0.f;
        #pragma unroll
        for (int dj = 0; dj < 8; ++dj) {
            float e = __expf((sc[di][dj] - m) * 0.17677669529663687f);
            sc[di][dj] = e;
            sum += e;
        }
        sum += __shfl_xor(sum, 8);
        sum += __shfl_xor(sum, 16);
        float inv = 1.f / sum;
        const int rb = h * 1088 + (ub + 8 * di) * 34;
        #pragma unroll
        for (int dj = 0; dj < 8; ++dj)
            pt[rb + us + 4 * dj] = f2bf(sc[di][dj] * inv);
    }
    __syncthreads();

    // ---- PV ----
    const int vc = qc + 64, d0 = us * 8;
    float o[4][8];
    #pragma unroll
    for (int di = 0; di < 4; ++di)
        #pragma unroll
        for (int dd = 0; dd < 8; ++dd) o[di][dd] = 0.f;

    for (int j = 0; j < 32; ++j) {
        float pv[4];
        #pragma unroll
        for (int di = 0; di < 4; ++di)
            pv[di] = bf2f(pt[h * 1088 + (ub + 8 * di) * 34 + j]);
        #pragma unroll
        for (int dq = 0; dq < 2; ++dq) {
            uint2 v = *(const uint2*)&s[j * LDR + vc + d0 + 4 * dq];
            float v0 = bflo(v.x), v1 = bfhi(v.x), v2 = bflo(v.y), v3 = bfhi(v.y);
            #pragma unroll
            for (int di = 0; di < 4; ++di) {
                o[di][dq * 4 + 0] = fmaf(pv[di], v0, o[di][dq * 4 + 0]);
                o[di][dq * 4 + 1] = fmaf(pv[di], v1, o[di][dq * 4 + 1]);
                o[di][dq * 4 + 2] = fmaf(pv[di], v2, o[di][dq * 4 + 2]);
                o[di][dq * 4 + 3] = fmaf(pv[di], v3, o[di][dq * 4 + 3]);
            }
        }
    }
    __syncthreads();   // all reads of s/pt done before overwriting with at

    // ---- bridge: o -> at (swizzled A layout) ----
    {
        const int col = h * 32 + d0;           // 8-col chunk this thread owns
        const int kb = col >> 6, c = (col & 63) >> 3;
        #pragma unroll
        for (int di = 0; di < 4; ++di) {
            const int i = ub + 8 * di;
            s16x8 ov;
            #pragma unroll
            for (int dd = 0; dd < 8; ++dd) ov[dd] = (short)f2bf(o[di][dd]);
            *(s16x8*)&at[kb * 2048 + i * 64 + ((c ^ (i & 7)) << 3)] = ov;
        }
    }

    // ---- phase B: pre = LN(at @ WoT^T + X), write bf16 ----
    const int wv = t >> 6, lane = t & 63, q = lane >> 4, l16 = lane & 15;
    const int wc = wv * 64;
    const int r0 = g * 32;
    f32x4 acc[2][4] = {};

    for (int k0 = 0; k0 < 256; k0 += 64) {
        __syncthreads();
        stage<256>(WoT, 0, 256, k0, Bs, wv, lane);
        __builtin_amdgcn_s_waitcnt(0);
        __syncthreads();
        const unsigned short* atk = at + (k0 >> 6) * 2048;
        #pragma unroll
        for (int kk2 = 0; kk2 < 2; ++kk2) {
            s16x8 af[2], bfr[4];
            #pragma unroll
            for (int mf = 0; mf < 2; ++mf)
                af[mf] = fragld(atk, mf * 16 + l16, kk2 * 4 + q);
            #pragma unroll
            for (int nf = 0; nf < 4; ++nf)
                bfr[nf] = fragld(Bs, wc + nf * 16 + l16, kk2 * 4 + q);
            #pragma unroll
            for (int mf = 0; mf < 2; ++mf)
                #pragma unroll
                for (int nf = 0; nf < 4; ++nf)
                    acc[mf][nf] = __builtin_amdgcn_mfma_f32_16x16x32_bf16(af[mf], bfr[nf], acc[mf][nf], 0, 0, 0);
        }
    }

    // + residual X (fp32)
    #pragma unroll
    for (int mf = 0; mf < 2; ++mf)
        #pragma unroll
        for (int nf = 0; nf < 4; ++nf) {
            const int cg = wc + nf * 16 + l16;
            #pragma unroll
            for (int r = 0; r < 4; ++r)
                acc[mf][nf][r] += X[(size_t)(r0 + mf * 16 + q * 4 + r) * NH + cg];
        }

    // LN partial sums
    #pragma unroll
    for (int mf = 0; mf < 2; ++mf) {
        float sp[4] = {0.f, 0.f, 0.f, 0.f}, ssp[4] = {0.f, 0.f, 0.f, 0.f};
        #pragma unroll
        for (int nf = 0; nf < 4; ++nf)
            #pragma unroll
            for (int r = 0; r < 4; ++r) {
                float v = acc[mf][nf][r];
                sp[r] += v; ssp[r] += v * v;
            }
        #pragma unroll
        for (int off = 1; off < 16; off <<= 1)
            #pragma unroll
            for (int r = 0; r < 4; ++r) {
                sp[r]  += __shfl_xor(sp[r],  off);
                ssp[r] += __shfl_xor(ssp[r], off);
            }
        if (l16 == 0)
            #pragma unroll
            for (int r = 0; r < 4; ++r)
                partial[wv * 32 + mf * 16 + q * 4 + r] = make_float2(sp[r], ssp[r]);
    }
    __syncthreads();
    if (t < 32) {
        float sv = 0.f, ssv = 0.f;
        #pragma unroll
        for (int w = 0; w < 4; ++w) { sv += partial[w * 32 + t].x; ssv += partial[w * 32 + t].y; }
        float mu  = sv * (1.f / 256.f);
        float var = ssv * (1.f / 256.f) - mu * mu;
        stats[t] = make_float2(mu, rsqrtf(var + LN_EPS));
    }
    __syncthreads();

    #pragma unroll
    for (int mf = 0; mf < 2; ++mf)
        #pragma unroll
        for (int nf = 0; nf < 4; ++nf) {
            const int cg = wc + nf * 16 + l16;
            const float gm = gamma[cg], bt = beta[cg];
            #pragma unroll
            for (int r = 0; r < 4; ++r) {
                const int rl = mf * 16 + q * 4 + r;
                const float2 st = stats[rl];
                float v = (acc[mf][nf][r] - st.x) * st.y * gm + bt;
                preb[(size_t)(r0 + rl) * NH + cg] = f2bf(v);
            }
        }
}

// ---------------------------------------------------------------------------
extern "C" void kernel_launch(void* const* d_in, const int* in_sizes, int n_in,
                              void* d_out, int out_size, void* d_ws, size_t ws_size,
                              hipStream_t stream) {
    const float* X      = (const float*)d_in[0];
    const float* W_qkv  = (const float*)d_in[2];
    const float* W_o    = (const float*)d_in[3];
    const float* ln1_g  = (const float*)d_in[4];
    const float* ln1_b  = (const float*)d_in[5];
    const float* W_i    = (const float*)d_in[6];
    const float* W_out2 = (const float*)d_in[7];
    const float* ln2_g  = (const float*)d_in[8];
    const float* ln2_b  = (const float*)d_in[9];
    float* out = (float*)d_out;

    char* ws = (char*)d_ws;
    unsigned short* Xbf   = (unsigned short*)(ws);                 //  8.0 MB
    unsigned short* qkvb  = (unsigned short*)(ws + 8388608);       // 25.2 MB
    unsigned short* preb  = (unsigned short*)(ws + 58720256);      //  8.0 MB
    unsigned short* WqkvT = (unsigned short*)(ws + 67108864);
    unsigned short* WoT   = (unsigned short*)(ws + 67502080);
    unsigned short* WiT   = (unsigned short*)(ws + 67633152);
    unsigned short* Wo2T  = (unsigned short*)(ws + 68157440);
    unsigned short* interb = (unsigned short*)(ws);                // 33.5 MB alias (Xbf+qkvb dead)

    dim3 blk(256);
    hipLaunchKernelGGL(prep, dim3(768 + V * D / 4 / 256), blk, 0, stream,
                       X, Xbf, W_qkv, W_o, W_i, W_out2, WqkvT, WoT, WiT, Wo2T);

    hipLaunchKernelGGL((gemm128<D, THREE_NH, 0>), dim3(V / 128 * (THREE_NH / 128)), blk, 0, stream,
                       Xbf, WqkvT, qkvb);
    hipLaunchKernelGGL(attln, dim3(V / 32), blk, 0, stream,
                       qkvb, WoT, X, ln1_g, ln1_b, preb);
    hipLaunchKernelGGL((gemm128<D, IDIM, 1>), dim3(V / 128 * (IDIM / 128)), blk, 0, stream,
                       preb, WiT, interb);
    hipLaunchKernelGGL((gemm_ln<IDIM, true, true>), dim3(V / 32), blk, 0, stream,
                       interb, Wo2T, (const void*)preb, ln2_g, ln2_b, out, (unsigned short*)nullptr);
}